// Round 15
// baseline (209.527 us; speedup 1.0000x reference)
//
#include <hip/hip_runtime.h>
#include <hip/hip_fp16.h>

#define WAY 5
#define NQ 75
#define P 400              // 20*20 positions
#define PS (P*64)          // 25600 elements per sample
#define NPAIR (NQ*WAY)     // 375
#define TEMP_INV 0.2f      // 1/5.0
#define LOG2E 1.4426950408889634f

typedef unsigned short u16;
typedef _Float16 f16;
typedef __attribute__((ext_vector_type(8))) _Float16 f16x8;
typedef __attribute__((ext_vector_type(2))) _Float16 F16x2;
typedef __attribute__((ext_vector_type(2))) __fp16 h16x2;   // cvt_pkrtz return type
typedef __attribute__((ext_vector_type(4))) float f32x4;

// DPP row_ror reduction: sum over each 16-lane row, pure VALU (no LDS pipe).
template <int CTRL>
__device__ __forceinline__ float dpp_add_ror(float v) {
  const int x = __builtin_amdgcn_update_dpp(0, __float_as_int(v), CTRL, 0xF, 0xF, true);
  return v + __int_as_float(x);
}
__device__ __forceinline__ float sum16(float v) {
  v = dpp_add_ror<0x121>(v);   // row_ror:1
  v = dpp_add_ror<0x122>(v);   // row_ror:2
  v = dpp_add_ror<0x124>(v);   // row_ror:4
  v = dpp_add_ror<0x128>(v);   // row_ror:8
  return v;                    // every lane: sum of its 16-lane row
}
__device__ __forceinline__ float wave_sum(float v) {
  v = sum16(v);
  v += __shfl_xor(v, 16); v += __shfl_xor(v, 32);
  return v;
}

__device__ __forceinline__ __half2 pk2(float a, float b) {
  h16x2 t = __builtin_amdgcn_cvt_pkrtz(a, b);
  return __builtin_bit_cast(__half2, t);
}
__device__ __forceinline__ float hdot2(__half2 a, __half2 b, float c) {
  return __builtin_amdgcn_fdot2(__builtin_bit_cast(F16x2, a),
                                __builtin_bit_cast(F16x2, b), c, false);
}

// ---------------- prep: normalize_feature -> conv1x1 -> BN -> ReLU -> L2norm ----------------
// 800 blocks = 80 samples x 10 chunks of 40 positions, 8 waves each (5 pos/wave).
__global__ __launch_bounds__(512) void prep_kernel(
    const float* __restrict__ spt, const float* __restrict__ qry,
    const float* __restrict__ conv_w,
    const float* __restrict__ bng, const float* __restrict__ bnb,
    const float* __restrict__ bnm, const float* __restrict__ bnv,
    f16* __restrict__ sA, f16* __restrict__ qA,
    f16* __restrict__ snT, f16* __restrict__ qnT)
{
  __shared__ float xt[40 * 68];                        // stride 68 floats = 272B (16B-aligned)
  const int tid = threadIdx.x;
  const int n = blockIdx.x / 10, p0 = (blockIdx.x - n * 10) * 40;
  const float* src = (n < WAY) ? (spt + n * PS) : (qry + (n - WAY) * PS);
  const int lane = tid & 63, wv = tid >> 6;

  // per-lane weight row W[lane][0..63] (conv_w is [o][c] row-major)
  f32x4 wr[16];
#pragma unroll
  for (int j = 0; j < 16; ++j) wr[j] = *(const f32x4*)(conv_w + lane * 64 + j * 4);
  float wsum = 0.f;
#pragma unroll
  for (int j = 0; j < 16; ++j) wsum += (wr[j][0] + wr[j][1]) + (wr[j][2] + wr[j][3]);

  for (int i = tid; i < 2560; i += 512) {
    const int c = i / 40, pp = i - c * 40;
    xt[pp * 68 + c] = src[c * 400 + p0 + pp];          // coalesced 40-float runs
  }
  __syncthreads();

  const float bs = bng[lane] * rsqrtf(bnv[lane] + 1e-5f);
  const float bm = bnm[lane], bb = bnb[lane];
  f16* dA; f16* dN;
  if (n < WAY) { dA = sA + n * PS; dN = snT + n * PS; }
  else { const int m = n - WAY; dA = qA + m * PS; dN = qnT + m * PS; }

  for (int i = 0; i < 5; ++i) {
    const int p = wv * 5 + i;
    const float x = xt[p * 68 + lane];
    const float mu = wave_sum(x) * (1.0f / 64.0f);
    dN[(p0 + p) * 64 + lane] = (f16)(x - mu);          // [pos][c] f16 for pooling
    float y0 = 0.f, y1 = 0.f, y2 = 0.f, y3 = 0.f;
#pragma unroll
    for (int j = 0; j < 16; ++j) {
      const f32x4 xv = *(const f32x4*)&xt[p * 68 + j * 4];  // broadcast (same addr all lanes)
      y0 = fmaf(wr[j][0], xv[0], y0);
      y1 = fmaf(wr[j][1], xv[1], y1);
      y2 = fmaf(wr[j][2], xv[2], y2);
      y3 = fmaf(wr[j][3], xv[3], y3);
    }
    float y = ((y0 + y1) + (y2 + y3)) - mu * wsum;     // == W.(x - mu)
    y = fmaf(y - bm, bs, bb);
    y = fmaxf(y, 0.f);
    const float n2 = wave_sum(y * y);
    const float rn = 1.0f / fmaxf(sqrtf(n2), 1e-8f);
    dA[(p0 + p) * 64 + lane] = (f16)(y * rn);          // fp16 RNE
  }
}

// ---------------- corr: X[a,b] = F1[a].F2[b]; per-b gaussnorm+softmax over a (400);
//                  attn[a] = sum_b w[a,b]; fused attention-weighted pooling. ----------------
// Block = (mode,pair), **5 waves (320 thr)**, 51.2KB LDS -> 3 blocks/CU (15 waves <= 16-wave
// VGPR cap), grid fully resident in one round, perfect 5x5=25 b-tile balance.
// Swapped MFMA: lane l15 = a, (g,r) = b-col. X packed by a-pairs; dot2/packed-exp math.
__global__ __launch_bounds__(320, 4) void corr_kernel(
    const f16* __restrict__ sA, const f16* __restrict__ qA,
    const f16* __restrict__ snT, const f16* __restrict__ qnT,
    float* __restrict__ pooled)
{
  __shared__ f16 f1[25600];           // 51.2 KB, XOR-swizzled rows of 128B
  const int bid = blockIdx.x;
  const int mode = (bid >= NPAIR) ? 1 : 0;
  const int pair = mode ? (bid - NPAIR) : bid;
  const int q = pair / WAY, w = pair - q * WAY;
  const f16 *F1, *F2;
  if (!mode) { F1 = sA + w * PS; F2 = qA + q * PS; }
  else       { F1 = qA + q * PS; F2 = sA + w * PS; }

  const int tid = threadIdx.x, lane = tid & 63, wv = tid >> 6;   // wv in 0..4
  const int l15 = lane & 15, g = (lane >> 4) & 3;

  // stage F1 into LDS, XOR-swizzled (rows of 128B; byte ^= (row&7)<<4)
  for (int i = tid; i < 3200; i += 320) {
    const unsigned sw = ((unsigned)(i * 16)) ^ ((((unsigned)i >> 3) & 7u) << 4);
    *(f16x8*)((char*)f1 + sw) = *(const f16x8*)(F1 + i * 8);
  }
  __syncthreads();

  const unsigned sx = ((unsigned)(l15 & 7)) << 4;
  const unsigned b0 = ((unsigned)(l15 * 128 + g * 16)) ^ sx;
  const unsigned b1 = ((unsigned)(l15 * 128 + g * 16 + 64)) ^ sx;
  const char* f1B = (const char*)f1;

  const __half2 one2 = __float2half2_rn(1.0f);
  const __half2 m10  = __halves2half2(__float2half_rn(1.0f), __float2half_rn(0.0f));

  float av[25];                       // per-lane attn partials (g-group slice), f32
#pragma unroll
  for (int t = 0; t < 25; ++t) av[t] = 0.f;

  for (int s = 0; s < 5; ++s) {
    const int tile = wv * 5 + s;                    // perfect balance: 5 sets per wave
    // A-operand: this set's 16 b-columns (from global, once per set)
    const int aoffB = (tile * 16 + l15) * 64 + g * 8;
    const f16x8 Ah0 = *(const f16x8*)(F2 + aoffB);
    const f16x8 Ah1 = *(const f16x8*)(F2 + aoffB + 32);

    __half2 px[4][13];                              // px[r][t] = X(a=2t, a=2t+1) for col r
    float sum[4] = {0.f, 0.f, 0.f, 0.f};
    float ssq[4] = {0.f, 0.f, 0.f, 0.f};
#pragma unroll
    for (int t = 0; t < 12; ++t) {
      const int at0 = 2 * t, at1 = 2 * t + 1;
      const f16x8 B00 = *(const f16x8*)(f1B + at0 * 2048 + b0);
      const f16x8 B01 = *(const f16x8*)(f1B + at0 * 2048 + b1);
      const f16x8 B10 = *(const f16x8*)(f1B + at1 * 2048 + b0);
      const f16x8 B11 = *(const f16x8*)(f1B + at1 * 2048 + b1);
      f32x4 c0 = {0.f, 0.f, 0.f, 0.f};
      c0 = __builtin_amdgcn_mfma_f32_16x16x32_f16(Ah0, B00, c0, 0, 0, 0);
      c0 = __builtin_amdgcn_mfma_f32_16x16x32_f16(Ah1, B01, c0, 0, 0, 0);
      f32x4 c1 = {0.f, 0.f, 0.f, 0.f};
      c1 = __builtin_amdgcn_mfma_f32_16x16x32_f16(Ah0, B10, c1, 0, 0, 0);
      c1 = __builtin_amdgcn_mfma_f32_16x16x32_f16(Ah1, B11, c1, 0, 0, 0);
#pragma unroll
      for (int r = 0; r < 4; ++r) {
        const __half2 p = pk2(c0[r], c1[r]);
        px[r][t] = p;
        sum[r] = hdot2(p, one2, sum[r]);
        ssq[r] = hdot2(p, p, ssq[r]);
      }
    }
    { // tail a-tile 24 (second half zero-padded)
      const f16x8 B00 = *(const f16x8*)(f1B + 24 * 2048 + b0);
      const f16x8 B01 = *(const f16x8*)(f1B + 24 * 2048 + b1);
      f32x4 c0 = {0.f, 0.f, 0.f, 0.f};
      c0 = __builtin_amdgcn_mfma_f32_16x16x32_f16(Ah0, B00, c0, 0, 0, 0);
      c0 = __builtin_amdgcn_mfma_f32_16x16x32_f16(Ah1, B01, c0, 0, 0, 0);
#pragma unroll
      for (int r = 0; r < 4; ++r) {
        const __half2 p = pk2(c0[r], 0.f);
        px[r][12] = p;
        sum[r] = hdot2(p, one2, sum[r]);            // +0 from pad
        ssq[r] = hdot2(p, p, ssq[r]);               // +0 from pad
      }
    }
    // per-column (b) stats over the 400 a-values: DPP row-sum over l15 group
    __half2 a2[4], b2[4];
#pragma unroll
    for (int r = 0; r < 4; ++r) {
      const float s_ = sum16(sum[r]);
      const float q_ = sum16(ssq[r]);
      const float m_ = s_ * (1.0f / 400.0f);
      float var = fmaf(-400.0f * m_, m_, q_) * (1.0f / 399.0f);  // ddof=1
      var = fmaxf(var, 0.f);
      const float al = rsqrtf(var + 1e-5f) * (TEMP_INV * LOG2E); // rstd/T, exp2 domain
      a2[r] = __float2half2_rn(al);
      b2[r] = __float2half2_rn(-m_ * al);                        // fold mean
    }
    // packed exp2 + per-column e-sums (f32 via dot2); tail masked (pad would give 2^beta)
    float se[4] = {0.f, 0.f, 0.f, 0.f};
#pragma unroll
    for (int t = 0; t < 13; ++t) {
      const __half2 msk = (t == 12) ? m10 : one2;
#pragma unroll
      for (int r = 0; r < 4; ++r) {
        const __half2 e = h2exp2(__hfma2(px[r][t], a2[r], b2[r]));
        px[r][t] = e;
        se[r] = hdot2(e, msk, se[r]);
      }
    }
    __half2 iv2[4];
#pragma unroll
    for (int r = 0; r < 4; ++r) {
      iv2[r] = __float2half2_rn(1.0f / sum16(se[r]));
    }
    // attn partials: av[a] += sum_r e[a,r]*inv[r]  (packed 4-term chain, f32 accumulate)
#pragma unroll
    for (int t = 0; t < 13; ++t) {
      __half2 acc = __hmul2(px[3][t], iv2[3]);
      acc = __hfma2(px[2][t], iv2[2], acc);
      acc = __hfma2(px[1][t], iv2[1], acc);
      acc = __hfma2(px[0][t], iv2[0], acc);
      av[2 * t] += __low2float(acc);
      if (t < 12) av[2 * t + 1] += __high2float(acc);
    }
  }
  // combine the 4 g-groups once per wave
#pragma unroll
  for (int at = 0; at < 25; ++at) {
    float v = av[at];
    v += __shfl_xor(v, 16); v += __shfl_xor(v, 32);
    av[at] = v;
  }
  __syncthreads();                                   // all waves done reading f1
  float* marea = (float*)f1;                         // reuse dead f1: [5][400] f32 + pbuf
  if (lane < 16) {
#pragma unroll
    for (int at = 0; at < 25; ++at) marea[wv * 400 + at * 16 + lane] = av[at];
  }
  __syncthreads();
  // merge the 5 private rows into row 0
  for (int a = tid; a < P; a += 320) {
    float s_ = marea[a];
#pragma unroll
    for (int k = 1; k < 5; ++k) s_ += marea[k * 400 + a];
    marea[a] = s_;
  }
  __syncthreads();
  // fused pooling: pooled[c] = (1/400) * sum_a attn[a] * Fn[a][c]; 80 positions/wave
  const f16* Fn = mode ? (qnT + q * PS) : (snT + w * PS);
  float pa0 = 0.f, pa1 = 0.f;
  for (int j = 0; j < 80; j += 2) {
    const int a = wv * 80 + j;
    pa0 = fmaf(marea[a],     (float)Fn[a * 64 + lane],       pa0);
    pa1 = fmaf(marea[a + 1], (float)Fn[(a + 1) * 64 + lane], pa1);
  }
  float* pbuf = marea + 2048;                        // dead region beyond merged row
  pbuf[wv * 64 + lane] = pa0 + pa1;
  __syncthreads();
  if (wv == 0) {
    float s_ = 0.f;
#pragma unroll
    for (int k = 0; k < 5; ++k) s_ += pbuf[k * 64 + lane];
    pooled[(mode * NPAIR + pair) * 64 + lane] = s_ * (1.0f / 400.0f);
  }
}

// ---------------- cosine: out[pair] = cos(spt_att, qry_att) * scale ----------------
__global__ __launch_bounds__(256) void cos_kernel(
    const float* __restrict__ pooled, const float* __restrict__ scale,
    float* __restrict__ out)
{
  const int pair = blockIdx.x * 4 + (threadIdx.x >> 6);
  const int lane = threadIdx.x & 63;
  if (pair >= NPAIR) return;
  const float sa = pooled[pair * 64 + lane];
  const float qa = pooled[(NPAIR + pair) * 64 + lane];
  const float d   = wave_sum(sa * qa);
  const float ns  = wave_sum(sa * sa);
  const float nq2 = wave_sum(qa * qa);
  if (lane == 0) {
    const float den = fmaxf(sqrtf(ns), 1e-6f) * fmaxf(sqrtf(nq2), 1e-6f);
    out[pair] = d / den * scale[0];
  }
}

extern "C" void kernel_launch(void* const* d_in, const int* in_sizes, int n_in,
                              void* d_out, int out_size, void* d_ws, size_t ws_size,
                              hipStream_t stream) {
  const float* spt    = (const float*)d_in[0];
  const float* qry    = (const float*)d_in[1];
  const float* conv_w = (const float*)d_in[2];
  const float* bng    = (const float*)d_in[3];
  const float* bnb    = (const float*)d_in[4];
  const float* bnm    = (const float*)d_in[5];
  const float* bnv    = (const float*)d_in[6];
  const float* scale  = (const float*)d_in[7];
  float* out = (float*)d_out;

  char* p = (char*)d_ws;
  f16* sA = (f16*)p;      p += (size_t)WAY * PS * 2;
  f16* qA = (f16*)p;      p += (size_t)NQ * PS * 2;
  f16* snT = (f16*)p;     p += (size_t)WAY * PS * 2;
  f16* qnT = (f16*)p;     p += (size_t)NQ * PS * 2;
  float* pooled = (float*)p;  p += (size_t)2 * NPAIR * 64 * 4;

  prep_kernel<<<dim3(800), dim3(512), 0, stream>>>(
      spt, qry, conv_w, bng, bnb, bnm, bnv, sA, qA, snT, qnT);
  corr_kernel<<<dim3(2 * NPAIR), dim3(320), 0, stream>>>(
      sA, qA, snT, qnT, pooled);
  cos_kernel<<<dim3((NPAIR + 3) / 4), dim3(256), 0, stream>>>(
      pooled, scale, out);
}

// Round 16
// 81.492 us; speedup vs baseline: 2.5711x; 2.5711x over previous
//
#include <hip/hip_runtime.h>
#include <hip/hip_fp16.h>

#define WAY 5
#define NQ 75
#define P 400              // 20*20 positions
#define PS (P*64)          // 25600 elements per sample
#define NPAIR (NQ*WAY)     // 375
#define TEMP_INV 0.2f      // 1/5.0
#define LOG2E 1.4426950408889634f

typedef unsigned short u16;
typedef _Float16 f16;
typedef __attribute__((ext_vector_type(8))) _Float16 f16x8;
typedef __attribute__((ext_vector_type(2))) _Float16 F16x2;
typedef __attribute__((ext_vector_type(2))) __fp16 h16x2;   // cvt_pkrtz return type
typedef __attribute__((ext_vector_type(4))) float f32x4;

// DPP row_ror reduction: sum over each 16-lane row, pure VALU (no LDS pipe).
template <int CTRL>
__device__ __forceinline__ float dpp_add_ror(float v) {
  const int x = __builtin_amdgcn_update_dpp(0, __float_as_int(v), CTRL, 0xF, 0xF, true);
  return v + __int_as_float(x);
}
__device__ __forceinline__ float sum16(float v) {
  v = dpp_add_ror<0x121>(v);   // row_ror:1
  v = dpp_add_ror<0x122>(v);   // row_ror:2
  v = dpp_add_ror<0x124>(v);   // row_ror:4
  v = dpp_add_ror<0x128>(v);   // row_ror:8
  return v;                    // every lane: sum of its 16-lane row
}
__device__ __forceinline__ float wave_sum(float v) {
  v = sum16(v);
  v += __shfl_xor(v, 16); v += __shfl_xor(v, 32);
  return v;
}

__device__ __forceinline__ __half2 pk2(float a, float b) {
  h16x2 t = __builtin_amdgcn_cvt_pkrtz(a, b);
  return __builtin_bit_cast(__half2, t);
}
__device__ __forceinline__ float hdot2(__half2 a, __half2 b, float c) {
  return __builtin_amdgcn_fdot2(__builtin_bit_cast(F16x2, a),
                                __builtin_bit_cast(F16x2, b), c, false);
}

// ---------------- prep: normalize_feature -> conv1x1 -> BN -> ReLU -> L2norm ----------------
// 800 blocks = 80 samples x 10 chunks of 40 positions, 8 waves each (5 pos/wave).
// Lane = output channel. Weights held in 16 f32x4 regs/lane; x-row read via
// same-address (broadcast) ds_read_b128; mean-subtract folded: y = W.x - mu*sum(W).
__global__ __launch_bounds__(512) void prep_kernel(
    const float* __restrict__ spt, const float* __restrict__ qry,
    const float* __restrict__ conv_w,
    const float* __restrict__ bng, const float* __restrict__ bnb,
    const float* __restrict__ bnm, const float* __restrict__ bnv,
    f16* __restrict__ sA, f16* __restrict__ qA,
    f16* __restrict__ snT, f16* __restrict__ qnT)
{
  __shared__ float xt[40 * 68];                        // stride 68 floats = 272B (16B-aligned)
  const int tid = threadIdx.x;
  const int n = blockIdx.x / 10, p0 = (blockIdx.x - n * 10) * 40;
  const float* src = (n < WAY) ? (spt + n * PS) : (qry + (n - WAY) * PS);
  const int lane = tid & 63, wv = tid >> 6;

  // per-lane weight row W[lane][0..63] (conv_w is [o][c] row-major)
  f32x4 wr[16];
#pragma unroll
  for (int j = 0; j < 16; ++j) wr[j] = *(const f32x4*)(conv_w + lane * 64 + j * 4);
  float wsum = 0.f;
#pragma unroll
  for (int j = 0; j < 16; ++j) wsum += (wr[j][0] + wr[j][1]) + (wr[j][2] + wr[j][3]);

  for (int i = tid; i < 2560; i += 512) {
    const int c = i / 40, pp = i - c * 40;
    xt[pp * 68 + c] = src[c * 400 + p0 + pp];          // coalesced 40-float runs
  }
  __syncthreads();

  const float bs = bng[lane] * rsqrtf(bnv[lane] + 1e-5f);
  const float bm = bnm[lane], bb = bnb[lane];
  f16* dA; f16* dN;
  if (n < WAY) { dA = sA + n * PS; dN = snT + n * PS; }
  else { const int m = n - WAY; dA = qA + m * PS; dN = qnT + m * PS; }

  for (int i = 0; i < 5; ++i) {
    const int p = wv * 5 + i;
    const float x = xt[p * 68 + lane];
    const float mu = wave_sum(x) * (1.0f / 64.0f);
    dN[(p0 + p) * 64 + lane] = (f16)(x - mu);          // [pos][c] f16 for pooling
    float y0 = 0.f, y1 = 0.f, y2 = 0.f, y3 = 0.f;
#pragma unroll
    for (int j = 0; j < 16; ++j) {
      const f32x4 xv = *(const f32x4*)&xt[p * 68 + j * 4];  // broadcast (same addr all lanes)
      y0 = fmaf(wr[j][0], xv[0], y0);
      y1 = fmaf(wr[j][1], xv[1], y1);
      y2 = fmaf(wr[j][2], xv[2], y2);
      y3 = fmaf(wr[j][3], xv[3], y3);
    }
    float y = ((y0 + y1) + (y2 + y3)) - mu * wsum;     // == W.(x - mu)
    y = fmaf(y - bm, bs, bb);
    y = fmaxf(y, 0.f);
    const float n2 = wave_sum(y * y);
    const float rn = 1.0f / fmaxf(sqrtf(n2), 1e-8f);
    dA[(p0 + p) * 64 + lane] = (f16)(y * rn);          // fp16 RNE
  }
}

// ---------------- corr: X[a,b] = F1[a].F2[b]; per-b gaussnorm+softmax over a (400);
//                  attn[a] = sum_b w[a,b]; fused attention-weighted pooling. ----------------
// Block = (mode,pair), 8 waves, 51.2KB LDS, (512,4) -> 2 blocks/CU, NO spill.
// Swapped MFMA: lane l15 = a, (g,r) = b-col. X packed by a-pairs; dot2/packed-exp math.
// 16-lane reductions on VALU via DPP row_ror (LDS pipe reserved for ds_read_b128).
__global__ __launch_bounds__(512, 4) void corr_kernel(
    const f16* __restrict__ sA, const f16* __restrict__ qA,
    const f16* __restrict__ snT, const f16* __restrict__ qnT,
    float* __restrict__ pooled)
{
  __shared__ f16 f1[25600];           // 51.2 KB, XOR-swizzled rows of 128B
  const int bid = blockIdx.x;
  const int mode = (bid >= NPAIR) ? 1 : 0;
  const int pair = mode ? (bid - NPAIR) : bid;
  const int q = pair / WAY, w = pair - q * WAY;
  const f16 *F1, *F2;
  if (!mode) { F1 = sA + w * PS; F2 = qA + q * PS; }
  else       { F1 = qA + q * PS; F2 = sA + w * PS; }

  const int tid = threadIdx.x, lane = tid & 63, wv = tid >> 6;
  const int l15 = lane & 15, g = (lane >> 4) & 3;

  // stage F1 into LDS, XOR-swizzled (rows of 128B; byte ^= (row&7)<<4)
  for (int i = tid; i < 3200; i += 512) {
    const unsigned sw = ((unsigned)(i * 16)) ^ ((((unsigned)i >> 3) & 7u) << 4);
    *(f16x8*)((char*)f1 + sw) = *(const f16x8*)(F1 + i * 8);
  }
  __syncthreads();

  const unsigned sx = ((unsigned)(l15 & 7)) << 4;
  const unsigned b0 = ((unsigned)(l15 * 128 + g * 16)) ^ sx;
  const unsigned b1 = ((unsigned)(l15 * 128 + g * 16 + 64)) ^ sx;
  const char* f1B = (const char*)f1;

  const __half2 one2 = __float2half2_rn(1.0f);
  const __half2 m10  = __halves2half2(__float2half_rn(1.0f), __float2half_rn(0.0f));

  float av[25];                       // per-lane attn partials (g-group slice), f32
#pragma unroll
  for (int t = 0; t < 25; ++t) av[t] = 0.f;

  for (int s = 0; s < 4; ++s) {
    const int tile = wv + 8 * s;
    if (tile >= 25) continue;                       // wave-uniform
    // A-operand: this set's 16 b-columns (from global, once per set)
    const int aoffB = (tile * 16 + l15) * 64 + g * 8;
    const f16x8 Ah0 = *(const f16x8*)(F2 + aoffB);
    const f16x8 Ah1 = *(const f16x8*)(F2 + aoffB + 32);

    __half2 px[4][13];                              // px[r][t] = X(a=2t, a=2t+1) for col r
    float sum[4] = {0.f, 0.f, 0.f, 0.f};
    float ssq[4] = {0.f, 0.f, 0.f, 0.f};
#pragma unroll
    for (int t = 0; t < 12; ++t) {
      const int at0 = 2 * t, at1 = 2 * t + 1;
      const f16x8 B00 = *(const f16x8*)(f1B + at0 * 2048 + b0);
      const f16x8 B01 = *(const f16x8*)(f1B + at0 * 2048 + b1);
      const f16x8 B10 = *(const f16x8*)(f1B + at1 * 2048 + b0);
      const f16x8 B11 = *(const f16x8*)(f1B + at1 * 2048 + b1);
      f32x4 c0 = {0.f, 0.f, 0.f, 0.f};
      c0 = __builtin_amdgcn_mfma_f32_16x16x32_f16(Ah0, B00, c0, 0, 0, 0);
      c0 = __builtin_amdgcn_mfma_f32_16x16x32_f16(Ah1, B01, c0, 0, 0, 0);
      f32x4 c1 = {0.f, 0.f, 0.f, 0.f};
      c1 = __builtin_amdgcn_mfma_f32_16x16x32_f16(Ah0, B10, c1, 0, 0, 0);
      c1 = __builtin_amdgcn_mfma_f32_16x16x32_f16(Ah1, B11, c1, 0, 0, 0);
#pragma unroll
      for (int r = 0; r < 4; ++r) {
        const __half2 p = pk2(c0[r], c1[r]);
        px[r][t] = p;
        sum[r] = hdot2(p, one2, sum[r]);
        ssq[r] = hdot2(p, p, ssq[r]);
      }
    }
    { // tail a-tile 24 (second half zero-padded)
      const f16x8 B00 = *(const f16x8*)(f1B + 24 * 2048 + b0);
      const f16x8 B01 = *(const f16x8*)(f1B + 24 * 2048 + b1);
      f32x4 c0 = {0.f, 0.f, 0.f, 0.f};
      c0 = __builtin_amdgcn_mfma_f32_16x16x32_f16(Ah0, B00, c0, 0, 0, 0);
      c0 = __builtin_amdgcn_mfma_f32_16x16x32_f16(Ah1, B01, c0, 0, 0, 0);
#pragma unroll
      for (int r = 0; r < 4; ++r) {
        const __half2 p = pk2(c0[r], 0.f);
        px[r][12] = p;
        sum[r] = hdot2(p, one2, sum[r]);            // +0 from pad
        ssq[r] = hdot2(p, p, ssq[r]);               // +0 from pad
      }
    }
    // per-column (b) stats over the 400 a-values: DPP row-sum over l15 group
    __half2 a2[4], b2[4];
#pragma unroll
    for (int r = 0; r < 4; ++r) {
      const float s_ = sum16(sum[r]);
      const float q_ = sum16(ssq[r]);
      const float m_ = s_ * (1.0f / 400.0f);
      float var = fmaf(-400.0f * m_, m_, q_) * (1.0f / 399.0f);  // ddof=1
      var = fmaxf(var, 0.f);
      const float al = rsqrtf(var + 1e-5f) * (TEMP_INV * LOG2E); // rstd/T, exp2 domain
      a2[r] = __float2half2_rn(al);
      b2[r] = __float2half2_rn(-m_ * al);                        // fold mean
    }
    // packed exp2 + per-column e-sums (f32 via dot2); tail masked (pad would give 2^beta)
    float se[4] = {0.f, 0.f, 0.f, 0.f};
#pragma unroll
    for (int t = 0; t < 13; ++t) {
      const __half2 msk = (t == 12) ? m10 : one2;
#pragma unroll
      for (int r = 0; r < 4; ++r) {
        const __half2 e = h2exp2(__hfma2(px[r][t], a2[r], b2[r]));
        px[r][t] = e;
        se[r] = hdot2(e, msk, se[r]);
      }
    }
    __half2 iv2[4];
#pragma unroll
    for (int r = 0; r < 4; ++r) {
      iv2[r] = __float2half2_rn(1.0f / sum16(se[r]));
    }
    // attn partials: av[a] += sum_r e[a,r]*inv[r]  (packed 4-term chain, f32 accumulate)
#pragma unroll
    for (int t = 0; t < 13; ++t) {
      __half2 acc = __hmul2(px[3][t], iv2[3]);
      acc = __hfma2(px[2][t], iv2[2], acc);
      acc = __hfma2(px[1][t], iv2[1], acc);
      acc = __hfma2(px[0][t], iv2[0], acc);
      av[2 * t] += __low2float(acc);
      if (t < 12) av[2 * t + 1] += __high2float(acc);
    }
  }
  // combine the 4 g-groups once per wave
#pragma unroll
  for (int at = 0; at < 25; ++at) {
    float v = av[at];
    v += __shfl_xor(v, 16); v += __shfl_xor(v, 32);
    av[at] = v;
  }
  __syncthreads();                                   // all waves done reading f1
  float* marea = (float*)f1;                         // reuse dead f1: [8][400] f32 + pbuf
  if (lane < 16) {
#pragma unroll
    for (int at = 0; at < 25; ++at) marea[wv * 400 + at * 16 + lane] = av[at];
  }
  __syncthreads();
  // merge the 8 private rows into row 0
  for (int a = tid; a < P; a += 512) {
    float s_ = marea[a];
#pragma unroll
    for (int k = 1; k < 8; ++k) s_ += marea[k * 400 + a];
    marea[a] = s_;
  }
  __syncthreads();
  // fused pooling: pooled[c] = (1/400) * sum_a attn[a] * Fn[a][c]
  const f16* Fn = mode ? (qnT + q * PS) : (snT + w * PS);
  float pa0 = 0.f, pa1 = 0.f;
  for (int j = 0; j < 50; j += 2) {
    const int a = wv * 50 + j;
    pa0 = fmaf(marea[a],     (float)Fn[a * 64 + lane],       pa0);
    pa1 = fmaf(marea[a + 1], (float)Fn[(a + 1) * 64 + lane], pa1);
  }
  float* pbuf = marea + 512;                         // dead region (rows 1+)
  pbuf[wv * 64 + lane] = pa0 + pa1;
  __syncthreads();
  if (wv == 0) {
    float s_ = 0.f;
#pragma unroll
    for (int k = 0; k < 8; ++k) s_ += pbuf[k * 64 + lane];
    pooled[(mode * NPAIR + pair) * 64 + lane] = s_ * (1.0f / 400.0f);
  }
}

// ---------------- cosine: out[pair] = cos(spt_att, qry_att) * scale ----------------
__global__ __launch_bounds__(256) void cos_kernel(
    const float* __restrict__ pooled, const float* __restrict__ scale,
    float* __restrict__ out)
{
  const int pair = blockIdx.x * 4 + (threadIdx.x >> 6);
  const int lane = threadIdx.x & 63;
  if (pair >= NPAIR) return;
  const float sa = pooled[pair * 64 + lane];
  const float qa = pooled[(NPAIR + pair) * 64 + lane];
  const float d   = wave_sum(sa * qa);
  const float ns  = wave_sum(sa * sa);
  const float nq2 = wave_sum(qa * qa);
  if (lane == 0) {
    const float den = fmaxf(sqrtf(ns), 1e-6f) * fmaxf(sqrtf(nq2), 1e-6f);
    out[pair] = d / den * scale[0];
  }
}

extern "C" void kernel_launch(void* const* d_in, const int* in_sizes, int n_in,
                              void* d_out, int out_size, void* d_ws, size_t ws_size,
                              hipStream_t stream) {
  const float* spt    = (const float*)d_in[0];
  const float* qry    = (const float*)d_in[1];
  const float* conv_w = (const float*)d_in[2];
  const float* bng    = (const float*)d_in[3];
  const float* bnb    = (const float*)d_in[4];
  const float* bnm    = (const float*)d_in[5];
  const float* bnv    = (const float*)d_in[6];
  const float* scale  = (const float*)d_in[7];
  float* out = (float*)d_out;

  char* p = (char*)d_ws;
  f16* sA = (f16*)p;      p += (size_t)WAY * PS * 2;
  f16* qA = (f16*)p;      p += (size_t)NQ * PS * 2;
  f16* snT = (f16*)p;     p += (size_t)WAY * PS * 2;
  f16* qnT = (f16*)p;     p += (size_t)NQ * PS * 2;
  float* pooled = (float*)p;  p += (size_t)2 * NPAIR * 64 * 4;

  prep_kernel<<<dim3(800), dim3(512), 0, stream>>>(
      spt, qry, conv_w, bng, bnb, bnm, bnv, sA, qA, snT, qnT);
  corr_kernel<<<dim3(2 * NPAIR), dim3(512), 0, stream>>>(
      sA, qA, snT, qnT, pooled);
  cos_kernel<<<dim3((NPAIR + 3) / 4), dim3(256), 0, stream>>>(
      pooled, scale, out);
}